// Round 3
// baseline (212.195 us; speedup 1.0000x reference)
//
#include <hip/hip_runtime.h>

#define T_SEQ 2048
#define C_DIM 128
#define S_QK 0.08838834764831845f

typedef __attribute__((ext_vector_type(8))) short bf16x8;
typedef __attribute__((ext_vector_type(4))) short bf16x4;
typedef __attribute__((ext_vector_type(4))) float f32x4;

// ---- workspace layout (bytes) ----
// qw  bf16 [8][2048][128]            @ 0         (4,194,304)
// kw  bf16 [8][2048][128]            @ 4194304   (4,194,304)
// vw  bf16 [8][128][2048] (V^T)      @ 8388608   (4,194,304)
// Opart f32 [8*72][64][128]          @ 12582912  (18,874,368)
// ml  float2 [8*72][64]              @ 31457280  (294,912)
// cnt u32 [256]                      @ 31752192  (1,024)
#define OPART_OFF 12582912UL
#define ML_OFF    31457280UL
#define CNT_OFF   31752192UL

// async global->LDS, 16B per lane; LDS dest is wave-uniform base + lane*16
#define GLOAD_LDS16(gp, lp)                                          \
    __builtin_amdgcn_global_load_lds(                                \
        (const __attribute__((address_space(1))) void*)(gp),         \
        (__attribute__((address_space(3))) void*)(lp), 16, 0, 0)

__device__ __forceinline__ unsigned short f2bf(float f) {
    union { float f; unsigned int u; } v; v.f = f;
    unsigned int r = v.u + 0x7FFFu + ((v.u >> 16) & 1u);
    return (unsigned short)(r >> 16);
}

// PV matrix op: D = A(4xbf16) * B(4xbf16) + C, 16x16x16
__device__ __forceinline__ f32x4 mfma16(bf16x4 a, bf16x4 b, f32x4 c) {
#if __has_builtin(__builtin_amdgcn_mfma_f32_16x16x16_bf16_1k)
    return __builtin_amdgcn_mfma_f32_16x16x16_bf16_1k(a, b, c, 0, 0, 0);
#elif __has_builtin(__builtin_amdgcn_mfma_f32_16x16x16_bf16)
    return __builtin_amdgcn_mfma_f32_16x16x16_bf16(a, b, c, 0, 0, 0);
#else
    f32x4 d = c;
    asm volatile("v_mfma_f32_16x16x16_bf16 %0, %1, %2, %0"
                 : "+v"(d) : "v"(a), "v"(b));
    return d;
#endif
}

// compact chunk-slot base within a batch, for qt>=8 (chunks of 8 key-tiles)
__device__ __forceinline__ int chunk_base(int qt) {
    int g = qt >> 3;                       // 1,2,3
    if (g == 1) return (qt - 8) * 2;
    if (g == 2) return 16 + (qt - 16) * 3;
    return 40 + (qt - 24) * 4;             // total 72 per batch
}

// ---------------------------------------------------------------------------
// proj (prep fused): one of q|k|vT = (bf16(x)) @ (bf16(W))^T.
// grid (256 row-tiles, 3), block 256. Block (0,0) also zeroes the merge
// ticket counters (attn is stream-ordered after proj).
// ---------------------------------------------------------------------------
__global__ __launch_bounds__(256) void proj_kernel(
    const float* __restrict__ x,
    const float* __restrict__ Wk, const float* __restrict__ Wq,
    const float* __restrict__ Wv,
    unsigned short* __restrict__ qo, unsigned short* __restrict__ ko,
    unsigned short* __restrict__ vto, unsigned* __restrict__ cnt)
{
    const int rt = blockIdx.x;             // 64-row tile over B*T
    const int z  = blockIdx.y;             // 0=q, 1=k, 2=v(transposed)
    const int tid  = threadIdx.x;
    const int lane = tid & 63;
    const int w    = tid >> 6;
    const int n16  = lane & 15;
    const int quad = lane >> 4;

    if (rt == 0 && z == 0) cnt[tid] = 0;   // reset merge tickets each launch

    __shared__ __align__(16) unsigned short Wl[128 * 136];   // 34816 B
    __shared__ __align__(16) unsigned short Xl[9216];        // 18432 B

    const float* Wsrc = (z == 0 ? Wq : z == 1 ? Wk : Wv);
    const float wscale = (z == 0) ? S_QK : 1.0f;
    #pragma unroll
    for (int i = 0; i < 16; ++i) {
        int e = (tid + i * 256) * 4;       // 16384 f32, 4 per op
        int r = e >> 7, c = e & 127;
        float4 v = *reinterpret_cast<const float4*>(Wsrc + e);
        float ax = v.x * wscale, ay = v.y * wscale;
        float az = v.z * wscale, aw = v.w * wscale;
        unsigned lo, hi;
        asm("v_cvt_pk_bf16_f32 %0, %1, %2" : "=v"(lo) : "v"(ax), "v"(ay));
        asm("v_cvt_pk_bf16_f32 %0, %1, %2" : "=v"(hi) : "v"(az), "v"(aw));
        uint2 o2; o2.x = lo; o2.y = hi;
        *reinterpret_cast<uint2*>(&Wl[r * 136 + c]) = o2;
    }
    const float* xrow = x + (size_t)rt * 64 * C_DIM;
    #pragma unroll
    for (int i = 0; i < 8; ++i) {
        int e = (tid + i * 256) * 4;       // 8192 f32
        int r = e >> 7, c = e & 127;
        float4 v = *reinterpret_cast<const float4*>(xrow + e);
        unsigned lo, hi;
        asm("v_cvt_pk_bf16_f32 %0, %1, %2" : "=v"(lo) : "v"(v.x), "v"(v.y));
        asm("v_cvt_pk_bf16_f32 %0, %1, %2" : "=v"(hi) : "v"(v.z), "v"(v.w));
        uint2 o2; o2.x = lo; o2.y = hi;
        *reinterpret_cast<uint2*>(&Xl[r * 136 + c]) = o2;
    }
    __syncthreads();

    const int arow = w * 16 + n16;
    bf16x8 afr[4];
    #pragma unroll
    for (int kk = 0; kk < 4; ++kk)
        afr[kk] = *reinterpret_cast<const bf16x8*>(&Xl[arow * 136 + kk * 32 + quad * 8]);

    f32x4 acc[8];
    #pragma unroll
    for (int nt = 0; nt < 8; ++nt) acc[nt] = (f32x4){0.f, 0.f, 0.f, 0.f};
    #pragma unroll
    for (int kk = 0; kk < 4; ++kk)
        #pragma unroll
        for (int nt = 0; nt < 8; ++nt) {
            bf16x8 bfr = *reinterpret_cast<const bf16x8*>(
                &Wl[(nt * 16 + n16) * 136 + kk * 32 + quad * 8]);
            acc[nt] = __builtin_amdgcn_mfma_f32_16x16x32_bf16(afr[kk], bfr, acc[nt], 0, 0, 0);
        }

    const int trow_base = w * 16 + quad * 4;
    __syncthreads();                       // all waves done reading Xl
    if (z < 2) {
        #pragma unroll
        for (int nt = 0; nt < 8; ++nt)
            #pragma unroll
            for (int r = 0; r < 4; ++r)
                Xl[(trow_base + r) * 136 + nt * 16 + n16] = f2bf(acc[nt][r]);
        __syncthreads();
        unsigned short* dst = (z == 0 ? qo : ko) + (size_t)rt * 64 * C_DIM;
        #pragma unroll
        for (int i = 0; i < 4; ++i) {
            int e = (tid + i * 256) * 8;
            int r = e >> 7, c = e & 127;
            *reinterpret_cast<uint4*>(dst + e) =
                *reinterpret_cast<const uint4*>(&Xl[r * 136 + c]);
        }
    } else {
        // transpose v tile: vT[d][t_local], row stride 72
        const int b  = rt >> 5;
        const int qt = rt & 31;
        #pragma unroll
        for (int nt = 0; nt < 8; ++nt)
            #pragma unroll
            for (int r = 0; r < 4; ++r)
                Xl[(nt * 16 + n16) * 72 + trow_base + r] = f2bf(acc[nt][r]);
        __syncthreads();
        unsigned short* dst = vto + (size_t)b * C_DIM * T_SEQ + (size_t)qt * 64;
        #pragma unroll
        for (int i = 0; i < 4; ++i) {
            int e = tid + i * 256;
            int d = e >> 3, cv = (e & 7) * 8;
            *reinterpret_cast<uint4*>(dst + (size_t)d * T_SEQ + cv) =
                *reinterpret_cast<const uint4*>(&Xl[d * 72 + cv]);
        }
    }
}

// ---------------------------------------------------------------------------
// attn: split-K flash attention; 32-key staged tiles, 16-key register
// substeps with P entirely in registers (swapped-operand identity:
// 16x16 MFMA C/D layout == 16x16x16 B-operand layout). Merge of <=4 split-K
// partials folded in via threadfence+atomic ticket (last arriver merges).
// grid 1024 linear; b = lin&7 (batch -> XCD L2 affinity).
// LDS 32.8 KB; VGPR-capped at 4 blocks/CU.
// Swizzles (source-side XOR == read-side XOR, both bank-uniform 2-way):
//   K (16 chunks/row):  c ^= (r & 7)
//   V ( 4 chunks/row):  c ^= (r & 3) ^ ((r >> 2) & 3)
// ---------------------------------------------------------------------------
__device__ __forceinline__ void stage_tile32(
    const char* ksb, const char* vsb,
    unsigned short* klbuf, unsigned short* vlbuf, int tid, int w)
{
    #pragma unroll
    for (int it = 0; it < 2; ++it) {                 // K: 32 rows x 16 chunks
        const int L = it * 256 + tid;
        const int r = L >> 4, c = L & 15;
        GLOAD_LDS16(ksb + r * 256 + ((c ^ (r & 7)) << 4),
                    klbuf + (size_t)(it * 256 + w * 64) * 8);
    }
    #pragma unroll
    for (int it = 0; it < 2; ++it) {                 // V^T: 128 rows x 4 chunks
        const int L = it * 256 + tid;
        const int r = L >> 2, c = L & 3;
        GLOAD_LDS16(vsb + (size_t)r * (T_SEQ * 2) +
                        ((c ^ (r & 3) ^ ((r >> 2) & 3)) << 4),
                    vlbuf + (size_t)(it * 256 + w * 64) * 8);
    }
}

__global__ __launch_bounds__(256, 4) void attn_kernel(
    const unsigned short* __restrict__ qb,
    const unsigned short* __restrict__ kb,
    const unsigned short* __restrict__ vtb,
    float* __restrict__ opart, float2* __restrict__ mlbuf,
    unsigned* __restrict__ cnt,
    float* __restrict__ out)
{
    const int lin   = blockIdx.x;
    const int b     = lin & 7;             // batch -> XCD affinity
    const int rest  = lin >> 3;
    const int qt    = rest & 31;
    const int chunk = rest >> 5;
    if (chunk * 8 > qt) return;

    const int tid  = threadIdx.x;
    const int lane = tid & 63;
    const int w    = tid >> 6;
    const int n16  = lane & 15;
    const int quad = lane >> 4;

    __shared__ __align__(16) unsigned short Kl[2][32 * 128];   // 16384 B
    __shared__ __align__(16) unsigned short Vl[2][128 * 32];   // 16384 B
    __shared__ int lastflag;

    const size_t bT = (size_t)b * T_SEQ;
    const int qbase = qt * 64 + w * 16;
    const int ulim  = 4 * qt + w;          // last useful 16-key substep (wave w)

    const int st0 = chunk * 16;                        // 32-key stage index
    const int st1 = min(chunk * 16 + 16, 2 * qt + 2);

    const char* kbase = (const char*)(kb + bT * C_DIM);
    const char* vbase = (const char*)(vtb + (size_t)b * C_DIM * T_SEQ);

    // prologue: stage first tile (4 vmem ops/thread outstanding)
    stage_tile32(kbase + (size_t)st0 * 8192, vbase + (size_t)st0 * 64,
                 Kl[0], Vl[0], tid, w);

    bf16x8 qfr[4];
    #pragma unroll
    for (int kk = 0; kk < 4; ++kk)
        qfr[kk] = *reinterpret_cast<const bf16x8*>(
            qb + (bT + qbase + n16) * C_DIM + kk * 32 + quad * 8);

    f32x4 o[8];
    #pragma unroll
    for (int ct = 0; ct < 8; ++ct) o[ct] = (f32x4){0.f, 0.f, 0.f, 0.f};
    float m_ = -INFINITY, l_ = 0.f;

    // per-lane constants for swizzled reads
    const int kx  = n16 & 7;                               // K chunk xor
    const int sig = (n16 & 3) ^ ((n16 >> 2) & 3);          // V chunk xor
    //   vfr (shorts): d*32 + ((sub*2 + (quad>>1)) ^ sig)*8 + (quad&1)*4
    const int vof0 = n16 * 32 + (((quad >> 1) ^ sig) << 3) + (quad & 1) * 4;
    const int vof1 = n16 * 32 + ((((quad >> 1) + 2) ^ sig) << 3) + (quad & 1) * 4;

    int cur = 0;
    for (int st = st0; st < st1; ++st, cur ^= 1) {
        if (st + 1 < st1) {
            stage_tile32(kbase + (size_t)(st + 1) * 8192,
                         vbase + (size_t)(st + 1) * 64,
                         Kl[cur ^ 1], Vl[cur ^ 1], tid, w);
            asm volatile("s_waitcnt vmcnt(4)" ::: "memory");
        } else {
            asm volatile("s_waitcnt vmcnt(0)" ::: "memory");
        }
        __builtin_amdgcn_s_barrier();      // current tile resident in LDS

        const unsigned short* klc = Kl[cur];
        const unsigned short* vlc = Vl[cur];

        #pragma unroll
        for (int sub = 0; sub < 2; ++sub) {
            const int u = st * 2 + sub;                    // 16-key substep
            if (u <= ulim) {
                // QK^T (swapped): lane holds S^T[s=4*quad+r][q=n16]
                f32x4 s4 = (f32x4){0.f, 0.f, 0.f, 0.f};
                const unsigned short* krow = klc + (sub * 16 + n16) * 128;
                __builtin_amdgcn_s_setprio(1);
                #pragma unroll
                for (int kk = 0; kk < 4; ++kk) {
                    bf16x8 kfr = *reinterpret_cast<const bf16x8*>(
                        krow + (((kk * 4 + quad) ^ kx) << 3));
                    s4 = __builtin_amdgcn_mfma_f32_16x16x32_bf16(kfr, qfr[kk], s4, 0, 0, 0);
                }
                __builtin_amdgcn_s_setprio(0);

                if (u == ulim) {                           // diagonal substep
                    #pragma unroll
                    for (int r = 0; r < 4; ++r) {
                        int sabs = u * 16 + quad * 4 + r;
                        if (sabs > qbase + n16) s4[r] = -1e30f;
                    }
                }

                // online softmax (per-lane q-row, reduce across quads)
                float pmax = fmaxf(fmaxf(s4[0], s4[1]), fmaxf(s4[2], s4[3]));
                pmax = fmaxf(pmax, __shfl_xor(pmax, 16));
                pmax = fmaxf(pmax, __shfl_xor(pmax, 32));
                if (pmax > m_ + 8.f) {                     // T13 defer-rescale
                    float alpha = __expf(m_ - pmax);
                    l_ *= alpha;
                    #pragma unroll
                    for (int ct = 0; ct < 8; ++ct) {
                        o[ct][0] *= alpha; o[ct][1] *= alpha;
                        o[ct][2] *= alpha; o[ct][3] *= alpha;
                    }
                    m_ = pmax;
                }
                float p0 = __expf(s4[0] - m_), p1 = __expf(s4[1] - m_);
                float p2 = __expf(s4[2] - m_), p3 = __expf(s4[3] - m_);
                float ts = (p0 + p1) + (p2 + p3);
                ts += __shfl_xor(ts, 16);
                ts += __shfl_xor(ts, 32);
                l_ += ts;

                // P in registers: C/D layout == 16x16x16 B-operand layout
                unsigned plo, phi;
                asm("v_cvt_pk_bf16_f32 %0, %1, %2" : "=v"(plo) : "v"(p0), "v"(p1));
                asm("v_cvt_pk_bf16_f32 %0, %1, %2" : "=v"(phi) : "v"(p2), "v"(p3));
                union { unsigned u2[2]; bf16x4 v; } pu;
                pu.u2[0] = plo; pu.u2[1] = phi;

                const int vof = sub ? vof1 : vof0;
                __builtin_amdgcn_s_setprio(1);
                #pragma unroll
                for (int ct = 0; ct < 8; ++ct) {
                    bf16x4 vfr = *reinterpret_cast<const bf16x4*>(vlc + ct * 512 + vof);
                    o[ct] = mfma16(vfr, pu.v, o[ct]);
                }
                __builtin_amdgcn_s_setprio(0);
            }
        }

        // all waves done reading this buffer before next iter overwrites it;
        // vmcnt (the prefetch) stays in flight.
        asm volatile("s_waitcnt lgkmcnt(0)" ::: "memory");
        __builtin_amdgcn_s_barrier();
    }

    // epilogue: lane holds O^T[d = ct*16+quad*4+(0..3)][q = n16]
    if (qt < 8) {
        float* outp = out + (bT + qbase + n16) * C_DIM;
        const float inv = 1.0f / l_;
        #pragma unroll
        for (int ct = 0; ct < 8; ++ct) {
            float4 r4;
            r4.x = o[ct][0] * inv; r4.y = o[ct][1] * inv;
            r4.z = o[ct][2] * inv; r4.w = o[ct][3] * inv;
            *reinterpret_cast<float4*>(outp + ct * 16 + quad * 4) = r4;
        }
        return;
    }

    const int nch  = (qt >> 3) + 1;
    const int base = b * 72 + chunk_base(qt);
    const int slot = base + chunk;
    float* op = opart + (size_t)slot * 8192 + (size_t)(w * 16 + n16) * 128;
    #pragma unroll
    for (int ct = 0; ct < 8; ++ct) {
        float4 r4;
        r4.x = o[ct][0]; r4.y = o[ct][1];
        r4.z = o[ct][2]; r4.w = o[ct][3];
        *reinterpret_cast<float4*>(op + ct * 16 + quad * 4) = r4;
    }
    if (quad == 0)
        mlbuf[(size_t)slot * 64 + w * 16 + n16] = make_float2(m_, l_);

    // ---- folded merge: last arriver for (b,qt) combines the partials ----
    __threadfence();                       // release our opart/ml stores
    __syncthreads();
    if (tid == 0) {
        unsigned old = atomicAdd(&cnt[b * 32 + qt], 1u);
        lastflag = (old == (unsigned)(nch - 1));
    }
    __syncthreads();
    if (!lastflag) return;
    __threadfence();                       // acquire other chunks' stores

    const int row = tid >> 2;
    const int c0  = (tid & 3) * 32;
    float2 t0 = mlbuf[(size_t)(base + 0) * 64 + row];
    float2 t1 = mlbuf[(size_t)(base + 1) * 64 + row];
    float2 t2 = (nch > 2) ? mlbuf[(size_t)(base + 2) * 64 + row]
                          : make_float2(-INFINITY, 0.f);
    float2 t3 = (nch > 3) ? mlbuf[(size_t)(base + 3) * 64 + row]
                          : make_float2(-INFINITY, 0.f);
    float M = fmaxf(fmaxf(t0.x, t1.x), fmaxf(t2.x, t3.x));
    float w0 = __expf(t0.x - M), w1 = __expf(t1.x - M);
    float w2 = __expf(t2.x - M), w3 = __expf(t3.x - M);
    float L = t0.y * w0 + t1.y * w1 + t2.y * w2 + t3.y * w3;
    const float inv = 1.0f / L;

    float* orow = out + ((size_t)(b * T_SEQ + qt * 64 + row)) * C_DIM;
    #pragma unroll
    for (int j = 0; j < 8; ++j) {
        int col = c0 + j * 4;
        const float* p0p = opart + (size_t)(base + 0) * 8192 + row * 128 + col;
        const float* p1p = opart + (size_t)(base + 1) * 8192 + row * 128 + col;
        float4 a0 = *reinterpret_cast<const float4*>(p0p);
        float4 a1 = *reinterpret_cast<const float4*>(p1p);
        float4 a2 = (nch > 2) ? *reinterpret_cast<const float4*>(
                        opart + (size_t)(base + 2) * 8192 + row * 128 + col)
                              : make_float4(0.f, 0.f, 0.f, 0.f);
        float4 a3 = (nch > 3) ? *reinterpret_cast<const float4*>(
                        opart + (size_t)(base + 3) * 8192 + row * 128 + col)
                              : make_float4(0.f, 0.f, 0.f, 0.f);
        float4 r4;
        r4.x = (a0.x * w0 + a1.x * w1 + a2.x * w2 + a3.x * w3) * inv;
        r4.y = (a0.y * w0 + a1.y * w1 + a2.y * w2 + a3.y * w3) * inv;
        r4.z = (a0.z * w0 + a1.z * w1 + a2.z * w2 + a3.z * w3) * inv;
        r4.w = (a0.w * w0 + a1.w * w1 + a2.w * w2 + a3.w * w3) * inv;
        *reinterpret_cast<float4*>(orow + col) = r4;
    }
}

extern "C" void kernel_launch(void* const* d_in, const int* in_sizes, int n_in,
                              void* d_out, int out_size, void* d_ws, size_t ws_size,
                              hipStream_t stream) {
    const float* x  = (const float*)d_in[0];
    const float* Wk = (const float*)d_in[1];
    const float* Wq = (const float*)d_in[2];
    const float* Wv = (const float*)d_in[3];

    unsigned short* qw  = (unsigned short*)d_ws;
    unsigned short* kw  = qw + 2097152;
    unsigned short* vw  = kw + 2097152;
    float*          opart = (float*)((char*)d_ws + OPART_OFF);
    float2*         mlb   = (float2*)((char*)d_ws + ML_OFF);
    unsigned*       cnt   = (unsigned*)((char*)d_ws + CNT_OFF);

    proj_kernel<<<dim3(256, 3), 256, 0, stream>>>(x, Wk, Wq, Wv, qw, kw, vw, cnt);
    attn_kernel<<<dim3(1024), 256, 0, stream>>>(qw, kw, vw, opart, mlb, cnt, (float*)d_out);
}

// Round 4
// 123.054 us; speedup vs baseline: 1.7244x; 1.7244x over previous
//
#include <hip/hip_runtime.h>

#define T_SEQ 2048
#define C_DIM 128
#define S_QK 0.08838834764831845f

typedef __attribute__((ext_vector_type(8))) short bf16x8;
typedef __attribute__((ext_vector_type(4))) short bf16x4;
typedef __attribute__((ext_vector_type(4))) float f32x4;
typedef __attribute__((ext_vector_type(2))) unsigned int u32x2;

// ---- workspace layout (bytes) ----  (d_ws arena is 256 MB: harness fill
// WRITE_SIZE = 262144 KB per re-poison)
// qw  bf16 [8][2048][128]            @ 0         (4,194,304)
// kw  bf16 [8][2048][128]            @ 4194304   (4,194,304)
// vw  bf16 [8][128][2048] (V^T)      @ 8388608   (4,194,304)
// Opart f32 [8*119][64][128]         @ 12582912  (31,195,136)
// ml  float2 [8*119][64]             @ 43778048  (487,424)
#define OPART_OFF 12582912UL
#define ML_OFF    43778048UL

// async global->LDS, 16B per lane; LDS dest is wave-uniform base + lane*16
#define GLOAD_LDS16(gp, lp)                                          \
    __builtin_amdgcn_global_load_lds(                                \
        (const __attribute__((address_space(1))) void*)(gp),         \
        (__attribute__((address_space(3))) void*)(lp), 16, 0, 0)

__device__ __forceinline__ unsigned short f2bf(float f) {
    union { float f; unsigned int u; } v; v.f = f;
    unsigned int r = v.u + 0x7FFFu + ((v.u >> 16) & 1u);
    return (unsigned short)(r >> 16);
}

// PV matrix op: D = A(4xbf16) * B(4xbf16) + C, 16x16x16
__device__ __forceinline__ f32x4 mfma16(bf16x4 a, bf16x4 b, f32x4 c) {
#if __has_builtin(__builtin_amdgcn_mfma_f32_16x16x16_bf16_1k)
    return __builtin_amdgcn_mfma_f32_16x16x16_bf16_1k(a, b, c, 0, 0, 0);
#elif __has_builtin(__builtin_amdgcn_mfma_f32_16x16x16_bf16)
    return __builtin_amdgcn_mfma_f32_16x16x16_bf16(a, b, c, 0, 0, 0);
#else
    f32x4 d = c;
    asm("v_mfma_f32_16x16x16_bf16 %0, %1, %2, %0" : "+v"(d) : "v"(a), "v"(b));
    return d;
#endif
}

// ---------------------------------------------------------------------------
// Split-K geometry: chunks of 5 key-tiles (64 keys each) = 10 32-key stages.
// Per batch: slot count = sum_qt ceil((qt+1)/5) = 119.
// Group g (1..7): qt in [5(g-1), 5g-1] has g chunks; group base B(g) =
// 5*g*(g-1)/2 slots.
// ---------------------------------------------------------------------------
__device__ __forceinline__ int base5(int qt) {
    int g = qt / 5 + 1;
    return 5 * g * (g - 1) / 2 + (qt - 5 * (g - 1)) * g;
}

// ---------------------------------------------------------------------------
// proj (prep fused): one of q|k|vT = (bf16(x)) @ (bf16(W))^T.
// grid (256 row-tiles, 3), block 256.
// ---------------------------------------------------------------------------
__global__ __launch_bounds__(256) void proj_kernel(
    const float* __restrict__ x,
    const float* __restrict__ Wk, const float* __restrict__ Wq,
    const float* __restrict__ Wv,
    unsigned short* __restrict__ qo, unsigned short* __restrict__ ko,
    unsigned short* __restrict__ vto)
{
    const int rt = blockIdx.x;             // 64-row tile over B*T
    const int z  = blockIdx.y;             // 0=q, 1=k, 2=v(transposed)
    const int tid  = threadIdx.x;
    const int lane = tid & 63;
    const int w    = tid >> 6;
    const int n16  = lane & 15;
    const int quad = lane >> 4;

    __shared__ __align__(16) unsigned short Wl[128 * 136];   // 34816 B
    __shared__ __align__(16) unsigned short Xl[9216];        // 18432 B

    const float* Wsrc = (z == 0 ? Wq : z == 1 ? Wk : Wv);
    const float wscale = (z == 0) ? S_QK : 1.0f;
    #pragma unroll
    for (int i = 0; i < 16; ++i) {
        int e = (tid + i * 256) * 4;       // 16384 f32, 4 per op
        int r = e >> 7, c = e & 127;
        float4 v = *reinterpret_cast<const float4*>(Wsrc + e);
        float ax = v.x * wscale, ay = v.y * wscale;
        float az = v.z * wscale, aw = v.w * wscale;
        unsigned lo, hi;
        asm("v_cvt_pk_bf16_f32 %0, %1, %2" : "=v"(lo) : "v"(ax), "v"(ay));
        asm("v_cvt_pk_bf16_f32 %0, %1, %2" : "=v"(hi) : "v"(az), "v"(aw));
        uint2 o2; o2.x = lo; o2.y = hi;
        *reinterpret_cast<uint2*>(&Wl[r * 136 + c]) = o2;
    }
    const float* xrow = x + (size_t)rt * 64 * C_DIM;
    #pragma unroll
    for (int i = 0; i < 8; ++i) {
        int e = (tid + i * 256) * 4;       // 8192 f32
        int r = e >> 7, c = e & 127;
        float4 v = *reinterpret_cast<const float4*>(xrow + e);
        unsigned lo, hi;
        asm("v_cvt_pk_bf16_f32 %0, %1, %2" : "=v"(lo) : "v"(v.x), "v"(v.y));
        asm("v_cvt_pk_bf16_f32 %0, %1, %2" : "=v"(hi) : "v"(v.z), "v"(v.w));
        uint2 o2; o2.x = lo; o2.y = hi;
        *reinterpret_cast<uint2*>(&Xl[r * 136 + c]) = o2;
    }
    __syncthreads();

    const int arow = w * 16 + n16;
    bf16x8 afr[4];
    #pragma unroll
    for (int kk = 0; kk < 4; ++kk)
        afr[kk] = *reinterpret_cast<const bf16x8*>(&Xl[arow * 136 + kk * 32 + quad * 8]);

    f32x4 acc[8];
    #pragma unroll
    for (int nt = 0; nt < 8; ++nt) acc[nt] = (f32x4){0.f, 0.f, 0.f, 0.f};
    #pragma unroll
    for (int kk = 0; kk < 4; ++kk)
        #pragma unroll
        for (int nt = 0; nt < 8; ++nt) {
            bf16x8 bfr = *reinterpret_cast<const bf16x8*>(
                &Wl[(nt * 16 + n16) * 136 + kk * 32 + quad * 8]);
            acc[nt] = __builtin_amdgcn_mfma_f32_16x16x32_bf16(afr[kk], bfr, acc[nt], 0, 0, 0);
        }

    const int trow_base = w * 16 + quad * 4;
    __syncthreads();                       // all waves done reading Xl
    if (z < 2) {
        #pragma unroll
        for (int nt = 0; nt < 8; ++nt)
            #pragma unroll
            for (int r = 0; r < 4; ++r)
                Xl[(trow_base + r) * 136 + nt * 16 + n16] = f2bf(acc[nt][r]);
        __syncthreads();
        unsigned short* dst = (z == 0 ? qo : ko) + (size_t)rt * 64 * C_DIM;
        #pragma unroll
        for (int i = 0; i < 4; ++i) {
            int e = (tid + i * 256) * 8;
            int r = e >> 7, c = e & 127;
            *reinterpret_cast<uint4*>(dst + e) =
                *reinterpret_cast<const uint4*>(&Xl[r * 136 + c]);
        }
    } else {
        // transpose v tile: vT[d][t_local], row stride 72
        const int b  = rt >> 5;
        const int qt = rt & 31;
        #pragma unroll
        for (int nt = 0; nt < 8; ++nt)
            #pragma unroll
            for (int r = 0; r < 4; ++r)
                Xl[(nt * 16 + n16) * 72 + trow_base + r] = f2bf(acc[nt][r]);
        __syncthreads();
        unsigned short* dst = vto + (size_t)b * C_DIM * T_SEQ + (size_t)qt * 64;
        #pragma unroll
        for (int i = 0; i < 4; ++i) {
            int e = tid + i * 256;
            int d = e >> 3, cv = (e & 7) * 8;
            *reinterpret_cast<uint4*>(dst + (size_t)d * T_SEQ + cv) =
                *reinterpret_cast<const uint4*>(&Xl[d * 72 + cv]);
        }
    }
}

// ---------------------------------------------------------------------------
// attn: split-K flash attention; 32-key staged tiles (double-buffered,
// global_load_lds w=16, counted vmcnt), 16-key register substeps with P in
// registers (16x16 C/D layout == 16x16x16 B-operand layout).
// grid 952 linear = 8 batches x 119 balanced chunks (max 10 stages/block);
// b = lin&7 (batch -> XCD L2 affinity). LDS 32.8 KB -> 4 blocks/CU.
// Swizzles (source-side XOR == read-side XOR, both bank-uniform 2-way):
//   K (16 chunks/row):  c ^= (r & 7)
//   V ( 4 chunks/row):  c ^= (r & 3) ^ ((r >> 2) & 3)
// ---------------------------------------------------------------------------
__device__ __forceinline__ void stage_tile32(
    const char* ksb, const char* vsb,
    unsigned short* klbuf, unsigned short* vlbuf, int tid, int w)
{
    #pragma unroll
    for (int it = 0; it < 2; ++it) {                 // K: 32 rows x 16 chunks
        const int L = it * 256 + tid;
        const int r = L >> 4, c = L & 15;
        GLOAD_LDS16(ksb + r * 256 + ((c ^ (r & 7)) << 4),
                    klbuf + (size_t)(it * 256 + w * 64) * 8);
    }
    #pragma unroll
    for (int it = 0; it < 2; ++it) {                 // V^T: 128 rows x 4 chunks
        const int L = it * 256 + tid;
        const int r = L >> 2, c = L & 3;
        GLOAD_LDS16(vsb + (size_t)r * (T_SEQ * 2) +
                        ((c ^ (r & 3) ^ ((r >> 2) & 3)) << 4),
                    vlbuf + (size_t)(it * 256 + w * 64) * 8);
    }
}

__global__ __launch_bounds__(256, 4) void attn_kernel(
    const unsigned short* __restrict__ qb,
    const unsigned short* __restrict__ kb,
    const unsigned short* __restrict__ vtb,
    float* __restrict__ opart, float2* __restrict__ mlbuf,
    float* __restrict__ out)
{
    const int lin = blockIdx.x;
    const int b   = lin & 7;               // batch -> XCD affinity
    const int s   = lin >> 3;              // slot 0..118
    int g = 1, gbase = 0;                  // decode (qt, chunk) from slot
    while (s - gbase >= 5 * g) { gbase += 5 * g; ++g; }
    const int qt    = 5 * (g - 1) + (s - gbase) / g;
    const int chunk = (s - gbase) % g;
    const int nch   = g;

    const int tid  = threadIdx.x;
    const int lane = tid & 63;
    const int w    = tid >> 6;
    const int n16  = lane & 15;
    const int quad = lane >> 4;

    __shared__ __align__(16) unsigned short Kl[2][32 * 128];   // 16384 B
    __shared__ __align__(16) unsigned short Vl[2][128 * 32];   // 16384 B

    const size_t bT = (size_t)b * T_SEQ;
    const int qbase = qt * 64 + w * 16;
    const int ulim  = 4 * qt + w;          // last useful 16-key substep (wave w)

    const int st0 = chunk * 10;                       // 32-key stage index
    const int st1 = min(st0 + 10, 2 * qt + 2);

    const char* kbase = (const char*)(kb + bT * C_DIM);
    const char* vbase = (const char*)(vtb + (size_t)b * C_DIM * T_SEQ);

    // prologue: stage first tile (4 vmem ops/thread outstanding)
    stage_tile32(kbase + (size_t)st0 * 8192, vbase + (size_t)st0 * 64,
                 Kl[0], Vl[0], tid, w);

    bf16x8 qfr[4];
    #pragma unroll
    for (int kk = 0; kk < 4; ++kk)
        qfr[kk] = *reinterpret_cast<const bf16x8*>(
            qb + (bT + qbase + n16) * C_DIM + kk * 32 + quad * 8);

    f32x4 o[8];
    #pragma unroll
    for (int ct = 0; ct < 8; ++ct) o[ct] = (f32x4){0.f, 0.f, 0.f, 0.f};
    float m_ = -INFINITY, l_ = 0.f;

    // per-lane constants for swizzled reads
    const int kx  = n16 & 7;                               // K chunk xor
    const int sig = (n16 & 3) ^ ((n16 >> 2) & 3);          // V chunk xor
    const int vof0 = n16 * 32 + (((quad >> 1) ^ sig) << 3) + (quad & 1) * 4;
    const int vof1 = n16 * 32 + ((((quad >> 1) + 2) ^ sig) << 3) + (quad & 1) * 4;

    int cur = 0;
    for (int st = st0; st < st1; ++st, cur ^= 1) {
        if (st + 1 < st1) {
            stage_tile32(kbase + (size_t)(st + 1) * 8192,
                         vbase + (size_t)(st + 1) * 64,
                         Kl[cur ^ 1], Vl[cur ^ 1], tid, w);
            asm volatile("s_waitcnt vmcnt(4)" ::: "memory");
        } else {
            asm volatile("s_waitcnt vmcnt(0)" ::: "memory");
        }
        __builtin_amdgcn_s_barrier();      // current tile resident in LDS

        const unsigned short* klc = Kl[cur];
        const unsigned short* vlc = Vl[cur];

        #pragma unroll
        for (int sub = 0; sub < 2; ++sub) {
            const int u = st * 2 + sub;                    // 16-key substep
            if (u <= ulim) {
                // QK^T (swapped): lane holds S^T[s=4*quad+r][q=n16]
                f32x4 s4 = (f32x4){0.f, 0.f, 0.f, 0.f};
                const unsigned short* krow = klc + (sub * 16 + n16) * 128;
                __builtin_amdgcn_s_setprio(1);
                #pragma unroll
                for (int kk = 0; kk < 4; ++kk) {
                    bf16x8 kfr = *reinterpret_cast<const bf16x8*>(
                        krow + (((kk * 4 + quad) ^ kx) << 3));
                    s4 = __builtin_amdgcn_mfma_f32_16x16x32_bf16(kfr, qfr[kk], s4, 0, 0, 0);
                }
                __builtin_amdgcn_s_setprio(0);

                if (u == ulim) {                           // diagonal substep
                    #pragma unroll
                    for (int r = 0; r < 4; ++r) {
                        int sabs = u * 16 + quad * 4 + r;
                        if (sabs > qbase + n16) s4[r] = -1e30f;
                    }
                }

                // online softmax (per-lane q-row, reduce across quads)
                float pmax = fmaxf(fmaxf(s4[0], s4[1]), fmaxf(s4[2], s4[3]));
                pmax = fmaxf(pmax, __shfl_xor(pmax, 16));
                pmax = fmaxf(pmax, __shfl_xor(pmax, 32));
                if (pmax > m_ + 8.f) {                     // T13 defer-rescale
                    float alpha = __expf(m_ - pmax);
                    l_ *= alpha;
                    #pragma unroll
                    for (int ct = 0; ct < 8; ++ct) {
                        o[ct][0] *= alpha; o[ct][1] *= alpha;
                        o[ct][2] *= alpha; o[ct][3] *= alpha;
                    }
                    m_ = pmax;
                }
                float p0 = __expf(s4[0] - m_), p1 = __expf(s4[1] - m_);
                float p2 = __expf(s4[2] - m_), p3 = __expf(s4[3] - m_);
                float ts = (p0 + p1) + (p2 + p3);
                ts += __shfl_xor(ts, 16);
                ts += __shfl_xor(ts, 32);
                l_ += ts;

                // P in registers: C/D layout == 16x16x16 B-operand layout
                unsigned plo, phi;
                asm("v_cvt_pk_bf16_f32 %0, %1, %2" : "=v"(plo) : "v"(p0), "v"(p1));
                asm("v_cvt_pk_bf16_f32 %0, %1, %2" : "=v"(phi) : "v"(p2), "v"(p3));
                u32x2 pp; pp.x = plo; pp.y = phi;
                bf16x4 pv = __builtin_bit_cast(bf16x4, pp);

                const int vof = sub ? vof1 : vof0;
                __builtin_amdgcn_s_setprio(1);
                #pragma unroll
                for (int ct = 0; ct < 8; ++ct) {
                    bf16x4 vfr = *reinterpret_cast<const bf16x4*>(vlc + ct * 512 + vof);
                    o[ct] = mfma16(vfr, pv, o[ct]);
                }
                __builtin_amdgcn_s_setprio(0);
            }
        }

        // all waves done reading this buffer before next iter overwrites it;
        // vmcnt (the prefetch) stays in flight.
        asm volatile("s_waitcnt lgkmcnt(0)" ::: "memory");
        __builtin_amdgcn_s_barrier();
    }

    // epilogue: lane holds O^T[d = ct*16+quad*4+(0..3)][q = n16]
    if (nch == 1) {
        float* outp = out + (bT + qbase + n16) * C_DIM;
        const float inv = 1.0f / l_;
        #pragma unroll
        for (int ct = 0; ct < 8; ++ct) {
            float4 r4;
            r4.x = o[ct][0] * inv; r4.y = o[ct][1] * inv;
            r4.z = o[ct][2] * inv; r4.w = o[ct][3] * inv;
            *reinterpret_cast<float4*>(outp + ct * 16 + quad * 4) = r4;
        }
        return;
    }

    const int slot = b * 119 + s;
    float* op = opart + (size_t)slot * 8192 + (size_t)(w * 16 + n16) * 128;
    #pragma unroll
    for (int ct = 0; ct < 8; ++ct) {
        float4 r4;
        r4.x = o[ct][0]; r4.y = o[ct][1];
        r4.z = o[ct][2]; r4.w = o[ct][3];
        *reinterpret_cast<float4*>(op + ct * 16 + quad * 4) = r4;
    }
    if (quad == 0)
        mlbuf[(size_t)slot * 64 + w * 16 + n16] = make_float2(m_, l_);
}

// ---------------------------------------------------------------------------
// merge: combine <=7 partials per (b, qt>=5). grid (27, 8), block 256.
// Fixed unroll-7 with predicates keeps mi/li/wgt in registers (no scratch).
// ---------------------------------------------------------------------------
__global__ __launch_bounds__(256) void merge_kernel(
    const float* __restrict__ opart, const float2* __restrict__ mlbuf,
    float* __restrict__ out)
{
    const int qt = 5 + blockIdx.x;
    const int b  = blockIdx.y;
    const int nch  = qt / 5 + 1;
    const int base = b * 119 + base5(qt);
    const int row = threadIdx.x >> 2;
    const int c0  = (threadIdx.x & 3) * 32;

    float mi[7], li[7], wgt[7];
    float M = -INFINITY;
    #pragma unroll
    for (int i = 0; i < 7; ++i) {
        if (i < nch) {
            float2 t = mlbuf[(size_t)(base + i) * 64 + row];
            mi[i] = t.x; li[i] = t.y;
            M = fmaxf(M, t.x);
        } else { mi[i] = -INFINITY; li[i] = 0.f; }
    }
    float L = 0.f;
    #pragma unroll
    for (int i = 0; i < 7; ++i) {
        wgt[i] = (i < nch) ? __expf(mi[i] - M) : 0.f;
        L += li[i] * wgt[i];
    }
    const float inv = 1.0f / L;

    float* orow = out + ((size_t)(b * T_SEQ + qt * 64 + row)) * C_DIM;
    #pragma unroll
    for (int j = 0; j < 8; ++j) {
        int col = c0 + j * 4;
        float ax = 0.f, ay = 0.f, az = 0.f, aw = 0.f;
        #pragma unroll
        for (int i = 0; i < 7; ++i) {
            if (i < nch) {
                float4 p = *reinterpret_cast<const float4*>(
                    opart + (size_t)(base + i) * 8192 + row * 128 + col);
                ax += wgt[i] * p.x; ay += wgt[i] * p.y;
                az += wgt[i] * p.z; aw += wgt[i] * p.w;
            }
        }
        float4 r4; r4.x = ax * inv; r4.y = ay * inv; r4.z = az * inv; r4.w = aw * inv;
        *reinterpret_cast<float4*>(orow + col) = r4;
    }
}

extern "C" void kernel_launch(void* const* d_in, const int* in_sizes, int n_in,
                              void* d_out, int out_size, void* d_ws, size_t ws_size,
                              hipStream_t stream) {
    const float* x  = (const float*)d_in[0];
    const float* Wk = (const float*)d_in[1];
    const float* Wq = (const float*)d_in[2];
    const float* Wv = (const float*)d_in[3];

    unsigned short* qw  = (unsigned short*)d_ws;
    unsigned short* kw  = qw + 2097152;
    unsigned short* vw  = kw + 2097152;
    float*          opart = (float*)((char*)d_ws + OPART_OFF);
    float2*         mlb   = (float2*)((char*)d_ws + ML_OFF);

    proj_kernel<<<dim3(256, 3), 256, 0, stream>>>(x, Wk, Wq, Wv, qw, kw, vw);
    attn_kernel<<<dim3(952), 256, 0, stream>>>(qw, kw, vw, opart, mlb, (float*)d_out);
    merge_kernel<<<dim3(27, 8), 256, 0, stream>>>(opart, mlb, (float*)d_out);
}